// Round 7
// baseline (364.786 us; speedup 1.0000x reference)
//
#include <hip/hip_runtime.h>
#include <hip/hip_bf16.h>

// Problem constants
#define B_    64
#define T_    1000
#define IN_   257
#define HID_  40
#define G3_   120
#define OUT_  257
#define M_    (B_*T_)   // 64000
#define NGI_  480
#define KP_   736       // padded KAN feature dim (720 real) = 92 groups of 8
#define KP1_  288       // padded GEMM1 K (257 real)
#define NP_   288       // padded OUT_ for k3 (18x16 cols)

// ws layout:
// gi0 240x64000 bf16 (layer0 gates, col-major; fwd | bwd)   = 30,720,000
// gi1 240x64000 bf16 (layer1 gates, col-major)              = 30,720,000
// P   column-block-major [92][64000][8] bf16                = 94,208,000
// Wk  288x736 bf16                                          =    423,936
// Wb  480x288 bf16                                          =    276,480
// WhT [2][128][64] bf16 (Whh1 gates x k, k40=bias, pad 0)   =     32,768
// h0R [2*M][64] bf16 row-major (k40=1.0, 41..63=0)          = 16,384,000
// h0C [2][40][M] bf16 col-major                             = 10,240,000
// ghC [2][120][M] bf16 col-major (gh = Whh1@h0 + bhh1)      = 30,720,000
#define OFF_GI1 30720000ull
#define OFF_P   61440000ull
#define OFF_WK  (OFF_P + 94208000ull)
#define OFF_WB  (OFF_WK + 423936ull)
#define OFF_WHT (OFF_WB + 276480ull)
#define OFF_H0R (OFF_WHT + 32768ull)
#define OFF_H0C (OFF_H0R + 16384000ull)
#define OFF_GHC (OFF_H0C + 10240000ull)
// end = OFF_GHC + 30,720,000 = 213,725,184 B

typedef __attribute__((ext_vector_type(8))) short bfx8;   // 8 bf16 = 4 VGPR
typedef __attribute__((ext_vector_type(4))) short bfx4;   // 8 B
typedef __attribute__((ext_vector_type(4))) float f32x4;  // MFMA C/D

__device__ __forceinline__ float sigf(float x){ return 1.0f/(1.0f + __expf(-x)); }
__device__ __forceinline__ float tanhfast(float x){ return 1.0f - 2.0f/(__expf(2.0f*x)+1.0f); }

__device__ __forceinline__ short bfbits(float v){
    __hip_bfloat16 h = __float2bfloat16(v);
    return *(short*)&h;
}
__device__ __forceinline__ float b2f(short s){
    return __uint_as_float(((unsigned)(unsigned short)s) << 16);
}

// Pack Wk[288][736] bf16 (rows 257..287 zero)
__global__ __launch_bounds__(256) void kprep(const float* __restrict__ bw,
                                             const float* __restrict__ sw,
                                             const float* __restrict__ ss,
                                             __hip_bfloat16* __restrict__ wk){
    int idx = blockIdx.x*256 + threadIdx.x;
    if (idx >= NP_*(KP_/8)) return;
    int o = idx / (KP_/8), q = idx % (KP_/8);
    bfx8 pk;
#pragma unroll
    for (int e=0;e<8;e++){
        int k = q*8 + e;
        float v = 0.0f;
        if (o < OUT_ && k < 720){
            if (k < 80) v = bw[o*80 + k];
            else { int i = (k-80)>>3, m = (k-80)&7; v = sw[(o*80+i)*8 + m] * ss[o*80+i]; }
        }
        pk[e] = bfbits(v);
    }
    *(bfx8*)((void*)&wk[(size_t)o*KP_ + q*8]) = pk;
}

// Pack Wb[480][288] bf16 from Wih_f | Wih_b, plus WhT[2][128][64] bf16:
// WhT[d][gate][k] = Whh1[d][gate][k] (k<40), bhh1[d][gate] (k==40), else 0.
__global__ __launch_bounds__(256) void wprep(const float* __restrict__ Wf,
                                             const float* __restrict__ Wbk,
                                             const float* __restrict__ Whh_f,
                                             const float* __restrict__ Whh_b,
                                             const float* __restrict__ bhh_f,
                                             const float* __restrict__ bhh_b,
                                             __hip_bfloat16* __restrict__ wb,
                                             __hip_bfloat16* __restrict__ wht){
    int idx = blockIdx.x*256 + threadIdx.x;
    if (idx < NGI_*(KP1_/8)){
        int n = idx / (KP1_/8), q = idx % (KP1_/8);
        bfx8 pk;
#pragma unroll
        for (int e=0;e<8;e++){
            int k = q*8 + e;
            float v = 0.0f;
            if (k < IN_) v = (n < 240) ? Wf[(size_t)n*IN_ + k] : Wbk[(size_t)(n-240)*IN_ + k];
            pk[e] = bfbits(v);
        }
        *(bfx8*)((void*)&wb[(size_t)n*KP1_ + q*8]) = pk;
        return;
    }
    int i2 = idx - NGI_*(KP1_/8);
    if (i2 >= 2*128*8) return;
    int d = i2 >> 10;            // 0..1
    int rest = i2 & 1023;
    int gate = rest >> 3, q = rest & 7;
    const float* Whh = d ? Whh_b : Whh_f;
    const float* bhh = d ? bhh_b : bhh_f;
    bfx8 pk;
#pragma unroll
    for (int e=0;e<8;e++){
        int k = q*8 + e;
        float v = 0.0f;
        if (gate < G3_){
            if (k < 40) v = Whh[G3_*HID_ + gate*HID_ + k];
            else if (k == 40) v = bhh[G3_ + gate];
        }
        pk[e] = bfbits(v);
    }
    *(bfx8*)((void*)&wht[(size_t)(d*128 + gate)*64 + q*8]) = pk;
}

// GEMM1 v2: barrier-free MFMA loop. One block = 64 rows x ALL 480 gates x K288.
// A (X, converted bf16) staged ONCE into LDS (full K, 46 KB); B fragments read
// directly from L2-resident Wb16 into registers. X is fetched exactly once.
// 4 waves: wr in {0,1} (32 rows each), wc in {0,1} (240 gates each).
__global__ __launch_bounds__(256) void k1_gemm(const float* __restrict__ X,
                                               const __hip_bfloat16* __restrict__ Wb16,
                                               const float* __restrict__ bf,
                                               const float* __restrict__ bb,
                                               __hip_bfloat16* __restrict__ gi0,
                                               __hip_bfloat16* __restrict__ gi1){
    __shared__ __hip_bfloat16 Asm[9*64*40];   // [ks][row][40] (32 used + pad)
    int tid = threadIdx.x, wave = tid>>6, lane = tid&63;
    int wr = wave>>1, wc = wave&1;
    int rl = lane&15, kq = lane>>4;
    int m0 = blockIdx.x*64;

    // ---- stage A once: 9 ksteps x 64 rows x 4 slots; thread = (row,slot) ----
    {
        int r = tid>>2, slot = tid&3;
#pragma unroll
        for (int ks=0;ks<9;ks++){
            int kg = ks*32 + slot*8;
            const float* xp = &X[(size_t)(m0+r)*IN_ + kg];
            bfx8 pk;
            if (kg + 7 < IN_){
                f32x4 x0 = *(const f32x4*)xp;
                f32x4 x1 = *(const f32x4*)(xp+4);
#pragma unroll
                for (int e=0;e<4;e++){ pk[e] = bfbits(x0[e]); pk[4+e] = bfbits(x1[e]); }
            } else {
#pragma unroll
                for (int e=0;e<8;e++){ int k = kg + e; pk[e] = (k < IN_) ? bfbits(xp[e]) : (short)0; }
            }
            *(bfx8*)((void*)&Asm[(ks*64 + r)*40 + slot*8]) = pk;
        }
    }
    __syncthreads();   // the ONLY barrier

    f32x4 acc[2][15];
#pragma unroll
    for (int f=0;f<2;f++)
#pragma unroll
        for (int j=0;j<15;j++) acc[f][j] = (f32x4){0.f,0.f,0.f,0.f};

    for (int ks=0; ks<9; ++ks){
        bfx8 a0 = *(bfx8*)((void*)&Asm[(ks*64 + wr*32 + rl)*40 + kq*8]);
        bfx8 a1 = *(bfx8*)((void*)&Asm[(ks*64 + wr*32 + 16 + rl)*40 + kq*8]);
        const __hip_bfloat16* bp = &Wb16[(size_t)(wc*240 + rl)*KP1_ + ks*32 + kq*8];
#pragma unroll
        for (int j=0;j<15;j++){
            bfx8 b = *(const bfx8*)&bp[(size_t)j*16*KP1_];
            acc[0][j] = __builtin_amdgcn_mfma_f32_16x16x32_bf16(a0, b, acc[0][j], 0,0,0);
            acc[1][j] = __builtin_amdgcn_mfma_f32_16x16x32_bf16(a1, b, acc[1][j], 0,0,0);
        }
    }

#pragma unroll
    for (int j=0;j<15;j++){
        int n = wc*240 + j*16 + rl;          // 0..479
        float bias = (n < 240) ? bf[n] : bb[n-240];
        int d  = (n >= 240) ? 1 : 0;
        int nn = n - 240*d;
#pragma unroll
        for (int f=0;f<2;f++){
            int mb = m0 + wr*32 + f*16 + kq*4;
            bfx4 v;
#pragma unroll
            for (int r=0;r<4;r++) v[r] = bfbits(acc[f][j][r] + bias);
            if (nn < 120){
                *(bfx4*)((void*)&gi0[(size_t)(d*120 + nn)*M_ + mb]) = v;
            } else {
                *(bfx4*)((void*)&gi1[(size_t)(d*120 + nn - 120)*M_ + mb]) = v;
            }
        }
    }
}

// k2a: pure pointwise layer-0. Writes h0R bf16 row-major (GEMM A operand,
// slot 40 = 1.0 for folded bias) and h0C bf16 col-major (for k2c).
__global__ __launch_bounds__(256) void k2a(const __hip_bfloat16* __restrict__ gi0,
                                           const float* __restrict__ bhh_f,
                                           const float* __restrict__ bhh_b,
                                           __hip_bfloat16* __restrict__ h0R,
                                           __hip_bfloat16* __restrict__ h0C){
    int blk = blockIdx.x;                       // 0..499; dir uniform
    int dir = (blk >= 250) ? 1 : 0;
    int m = (blk - dir*250)*256 + threadIdx.x;
    int b = m / T_, t = m - b*T_;
    int src = dir ? (b*T_ + (T_-1-t)) : m;
    const float* bhh0v = dir ? bhh_b : bhh_f;

    const __hip_bfloat16* g0 = gi0 + (size_t)(dir*120)*M_ + src;
    __hip_bfloat16* hc = h0C + (size_t)(dir*40)*M_ + m;
    float h0[HID_];
#pragma unroll
    for (int j=0;j<HID_;j++){
        float ir = b2f(*(const short*)&g0[(size_t)j*M_]);
        float iz = b2f(*(const short*)&g0[(size_t)(40+j)*M_]);
        float in = b2f(*(const short*)&g0[(size_t)(80+j)*M_]);
        float r = sigf(ir + bhh0v[j]);
        float z = sigf(iz + bhh0v[40+j]);
        float n = tanhfast(in + r*bhh0v[80+j]);
        h0[j] = (1.0f - z)*n;
        hc[(size_t)j*M_] = __float2bfloat16(h0[j]);
    }
    __hip_bfloat16* hr = h0R + (size_t)(dir*M_ + m)*64;
#pragma unroll
    for (int q=0;q<8;q++){
        bfx8 v;
#pragma unroll
        for (int e=0;e<8;e++){
            int idx = q*8 + e;
            float f = (idx < HID_) ? h0[idx] : (idx == HID_ ? 1.0f : 0.0f);
            v[e] = bfbits(f);
        }
        *(bfx8*)((void*)&hr[q*8]) = v;
    }
}

// k2b: gh GEMM on MFMA. C[256 m][128 gate] = h0R[256x64] @ WhT[128x64]^T per block.
// Single LDS stage (K=64), XOR-swizzled (128B rows -> 16-way conflict otherwise).
__global__ __launch_bounds__(512) void k2b(const __hip_bfloat16* __restrict__ h0R,
                                           const __hip_bfloat16* __restrict__ WhT,
                                           __hip_bfloat16* __restrict__ ghC){
    __shared__ __hip_bfloat16 Ah[256*64];
    __shared__ __hip_bfloat16 Bh[128*64];
    int tid = threadIdx.x, wave = tid>>6, lane = tid&63;
    int wr = wave>>1, wc = wave&1;
    int rl = lane&15, kq = lane>>4;
    int blk = blockIdx.x;
    int dir = (blk >= 250) ? 1 : 0;
    int m0 = (blk - dir*250)*256;

#pragma unroll
    for (int p=0;p<4;p++){
        int c = tid + p*512;
        int row = c>>3, q = c&7;
        bfx8 v = *(const bfx8*)&h0R[(size_t)(dir*M_ + m0 + row)*64 + q*8];
        *(bfx8*)((void*)&Ah[row*64 + ((q ^ (row&7))<<3)]) = v;
    }
#pragma unroll
    for (int p=0;p<2;p++){
        int c = tid + p*512;
        int row = c>>3, q = c&7;
        bfx8 v = *(const bfx8*)&WhT[(size_t)(dir*128 + row)*64 + q*8];
        *(bfx8*)((void*)&Bh[row*64 + ((q ^ (row&7))<<3)]) = v;
    }
    __syncthreads();

    f32x4 acc[4][4];
#pragma unroll
    for (int f=0;f<4;f++)
#pragma unroll
        for (int j=0;j<4;j++) acc[f][j] = (f32x4){0.f,0.f,0.f,0.f};

#pragma unroll
    for (int ks=0;ks<2;ks++){
        bfx8 a[4], bb[4];
#pragma unroll
        for (int f=0;f<4;f++){
            int row = wr*64 + f*16 + rl;
            a[f] = *(bfx8*)((void*)&Ah[row*64 + (((ks*4+kq) ^ (row&7))<<3)]);
        }
#pragma unroll
        for (int j=0;j<4;j++){
            int row = wc*64 + j*16 + rl;
            bb[j] = *(bfx8*)((void*)&Bh[row*64 + (((ks*4+kq) ^ (row&7))<<3)]);
        }
#pragma unroll
        for (int f=0;f<4;f++)
#pragma unroll
            for (int j=0;j<4;j++)
                acc[f][j] = __builtin_amdgcn_mfma_f32_16x16x32_bf16(a[f], bb[j], acc[f][j], 0,0,0);
    }
#pragma unroll
    for (int j=0;j<4;j++){
        int n = wc*64 + j*16 + rl;
        if (n < G3_){
#pragma unroll
            for (int f=0;f<4;f++){
                int mb = m0 + wr*64 + f*16 + kq*4;
                bfx4 v;
#pragma unroll
                for (int r=0;r<4;r++) v[r] = bfbits(acc[f][j][r]);
                *(bfx4*)((void*)&ghC[(size_t)(dir*G3_ + n)*M_ + mb]) = v;
            }
        }
    }
}

// k2c: thread = (m, dir, 8-feature group). Pure streaming pointwise:
// GRU layer-1 gates from gi1+ghC, silu, closed-form uniform cubic B-spline,
// coalesced bfx8 stores into column-block-major P. No LDS, no matvec.
__global__ __launch_bounds__(256, 4) void k2c(const __hip_bfloat16* __restrict__ gi1,
                                              const __hip_bfloat16* __restrict__ ghC,
                                              const __hip_bfloat16* __restrict__ h0C,
                                              __hip_bfloat16* __restrict__ P){
    int tid = threadIdx.x;
    int bb = blockIdx.x;            // 0..2499
    int mblk = bb % 250;
    int rest = bb / 250;            // 0..9
    int dir = rest / 5, grp = rest % 5;
    int m = mblk*256 + tid;
    int b = m / T_, t = m - b*T_;
    int src = dir ? (b*T_ + (T_-1-t)) : m;

    const __hip_bfloat16* g1 = gi1 + (size_t)(dir*120)*M_ + src;
    const __hip_bfloat16* gh = ghC + (size_t)(dir*120)*M_ + m;
    const __hip_bfloat16* hc = h0C + (size_t)(dir*40)*M_ + m;

    bfx8 sil;
#pragma unroll
    for (int jj=0;jj<8;jj++){
        int j = grp*8 + jj;
        float ir = b2f(*(const short*)&g1[(size_t)j*M_]);
        float iz = b2f(*(const short*)&g1[(size_t)(40+j)*M_]);
        float in = b2f(*(const short*)&g1[(size_t)(80+j)*M_]);
        float gr = b2f(*(const short*)&gh[(size_t)j*M_]);
        float gz = b2f(*(const short*)&gh[(size_t)(40+j)*M_]);
        float gn = b2f(*(const short*)&gh[(size_t)(80+j)*M_]);
        float r = sigf(ir + gr);
        float z = sigf(iz + gz);
        float n = tanhfast(in + r*gn);
        float h1 = (1.0f - z)*n + z*b2f(*(const short*)&hc[(size_t)j*M_]);
        sil[jj] = bfbits(h1 * sigf(h1));

        // closed-form uniform cubic B-spline: knots t_p=(p-3)*0.4-1, h=0.4
        float tt = (h1 + 1.0f) * 2.5f;
        float fs = floorf(tt);
        fs = fminf(fmaxf(fs, 0.0f), 4.0f);
        int sp = (int)fs;
        float u  = tt - fs;
        float um = 1.0f - u;
        float u2 = u*u, u3 = u2*u;
        float N0 = um*um*um * (1.0f/6.0f);
        float N1 = (3.0f*u3 - 6.0f*u2 + 4.0f) * (1.0f/6.0f);
        float N2 = (-3.0f*u3 + 3.0f*u2 + 3.0f*u + 1.0f) * (1.0f/6.0f);
        float N3 = u3 * (1.0f/6.0f);
        bfx8 pk;
#pragma unroll
        for (int i=0;i<8;i++){
            int d = i - sp;
            float v = (d==0)?N0 : (d==1)?N1 : (d==2)?N2 : (d==3)?N3 : 0.0f;
            pk[i] = bfbits(v);
        }
        *(bfx8*)((void*)&P[((size_t)(10 + dir*40 + j)*M_ + m)*8]) = pk;
    }
    *(bfx8*)((void*)&P[((size_t)(dir*5 + grp)*M_ + m)*8]) = sil;
    if (dir==0 && grp==0){   // zero K-pad groups 90,91 (logical cols 720..735)
        bfx8 z8 = {0,0,0,0,0,0,0,0};
        *(bfx8*)((void*)&P[((size_t)90*M_ + m)*8]) = z8;
        *(bfx8*)((void*)&P[((size_t)91*M_ + m)*8]) = z8;
    }
}

// GEMM2 (MFMA, pipelined dbuf): M-tile 256, N 288 (all), 8 waves (4x2).
__global__ __launch_bounds__(512) void k3_gemm(const __hip_bfloat16* __restrict__ P,
                                               const __hip_bfloat16* __restrict__ Wk,
                                               const float* __restrict__ slope,
                                               float* __restrict__ outp){
    __shared__ __hip_bfloat16 Asm[2][256*40];
    __shared__ __hip_bfloat16 Bsm[2][NP_*40];
    int tid = threadIdx.x, wave = tid>>6, lane = tid&63;
    int wr = wave>>1, wc = wave&1;
    int rl = lane&15, kq = lane>>4;
    int m0 = blockIdx.x*256;

    int qA = tid>>8, rA = tid&255;
    int rB = tid>>2, qB = tid&3;

    f32x4 acc[4][9];
#pragma unroll
    for (int f=0;f<4;f++)
#pragma unroll
        for (int j=0;j<9;j++) acc[f][j] = (f32x4){0.f,0.f,0.f,0.f};

    bfx8 ra[2], rb[3];

#define K3_LOAD(tt) { \
    int k8 = (tt)*4, k0 = (tt)*32; \
    ra[0] = *(const bfx8*)&P[((size_t)(k8+qA)*M_ + m0 + rA)*8]; \
    ra[1] = *(const bfx8*)&P[((size_t)(k8+qA+2)*M_ + m0 + rA)*8]; \
    rb[0] = *(const bfx8*)&Wk[(size_t)rB*KP_ + k0 + qB*8]; \
    rb[1] = *(const bfx8*)&Wk[(size_t)(rB+128)*KP_ + k0 + qB*8]; \
    if (tid < 128) rb[2] = *(const bfx8*)&Wk[(size_t)(rB+256)*KP_ + k0 + qB*8]; }

#define K3_WRITE(bufi) { \
    *(bfx8*)((void*)&Asm[bufi][rA*40 + qA*8]) = ra[0]; \
    *(bfx8*)((void*)&Asm[bufi][rA*40 + (qA+2)*8]) = ra[1]; \
    *(bfx8*)((void*)&Bsm[bufi][rB*40 + qB*8]) = rb[0]; \
    *(bfx8*)((void*)&Bsm[bufi][(rB+128)*40 + qB*8]) = rb[1]; \
    if (tid < 128) *(bfx8*)((void*)&Bsm[bufi][(rB+256)*40 + qB*8]) = rb[2]; }

    K3_LOAD(0); K3_WRITE(0); __syncthreads();
    for (int t=0; t<23; ++t){
        int c = t&1;
        if (t < 22) K3_LOAD(t+1);
        bfx8 a[4];
#pragma unroll
        for (int f=0;f<4;f++)
            a[f] = *(bfx8*)((void*)&Asm[c][(wr*64 + f*16 + rl)*40 + kq*8]);
#pragma unroll
        for (int j=0;j<9;j++){
            bfx8 b = *(bfx8*)((void*)&Bsm[c][(wc*144 + j*16 + rl)*40 + kq*8]);
#pragma unroll
            for (int f=0;f<4;f++)
                acc[f][j] = __builtin_amdgcn_mfma_f32_16x16x32_bf16(a[f], b, acc[f][j], 0,0,0);
        }
        if (t < 22) K3_WRITE(c^1);
        __syncthreads();
    }
#pragma unroll
    for (int j=0;j<9;j++){
        int n = wc*144 + j*16 + rl;
        if (n < OUT_){
            float sl = slope[n];
#pragma unroll
            for (int f=0;f<4;f++){
                int mb = m0 + wr*64 + f*16 + kq*4;
#pragma unroll
                for (int r=0;r<4;r++)
                    outp[(size_t)(mb+r)*OUT_ + n] = 1.2f * sigf(sl*acc[f][j][r]);
            }
        }
    }
}

extern "C" void kernel_launch(void* const* d_in, const int* in_sizes, int n_in,
                              void* d_out, int out_size, void* d_ws, size_t ws_size,
                              hipStream_t stream) {
    const float* x      = (const float*)d_in[0];
    const float* Wih_f  = (const float*)d_in[1];
    const float* Whh_f  = (const float*)d_in[2];
    const float* bih_f  = (const float*)d_in[3];
    const float* bhh_f  = (const float*)d_in[4];
    const float* Wih_b  = (const float*)d_in[5];
    const float* Whh_b  = (const float*)d_in[6];
    const float* bih_b  = (const float*)d_in[7];
    const float* bhh_b  = (const float*)d_in[8];
    const float* base_w = (const float*)d_in[9];
    const float* spl_w  = (const float*)d_in[10];
    const float* spl_s  = (const float*)d_in[11];
    const float* slope  = (const float*)d_in[12];

    char* ws = (char*)d_ws;
    __hip_bfloat16* gi0 = (__hip_bfloat16*)ws;
    __hip_bfloat16* gi1 = (__hip_bfloat16*)(ws + OFF_GI1);
    __hip_bfloat16* P   = (__hip_bfloat16*)(ws + OFF_P);
    __hip_bfloat16* Wk  = (__hip_bfloat16*)(ws + OFF_WK);
    __hip_bfloat16* Wb  = (__hip_bfloat16*)(ws + OFF_WB);
    __hip_bfloat16* WhT = (__hip_bfloat16*)(ws + OFF_WHT);
    __hip_bfloat16* h0R = (__hip_bfloat16*)(ws + OFF_H0R);
    __hip_bfloat16* h0C = (__hip_bfloat16*)(ws + OFF_H0C);
    __hip_bfloat16* ghC = (__hip_bfloat16*)(ws + OFF_GHC);
    float* outp = (float*)d_out;

    hipLaunchKernelGGL(kprep, dim3((NP_*(KP_/8) + 255)/256), dim3(256), 0, stream,
                       base_w, spl_w, spl_s, Wk);
    hipLaunchKernelGGL(wprep, dim3((NGI_*(KP1_/8) + 2048 + 255)/256), dim3(256), 0, stream,
                       Wih_f, Wih_b, Whh_f, Whh_b, bhh_f, bhh_b, Wb, WhT);
    hipLaunchKernelGGL(k1_gemm, dim3(1000), dim3(256), 0, stream,
                       x, Wb, bih_f, bih_b, gi0, gi1);
    hipLaunchKernelGGL(k2a, dim3(500), dim3(256), 0, stream,
                       gi0, bhh_f, bhh_b, h0R, h0C);
    hipLaunchKernelGGL(k2b, dim3(500), dim3(512), 0, stream,
                       h0R, WhT, ghC);
    hipLaunchKernelGGL(k2c, dim3(2500), dim3(256), 0, stream,
                       gi1, ghC, h0C, P);
    hipLaunchKernelGGL(k3_gemm, dim3(250), dim3(512), 0, stream,
                       P, Wk, slope, outp);
}

// Round 9
// 312.776 us; speedup vs baseline: 1.1663x; 1.1663x over previous
//
#include <hip/hip_runtime.h>
#include <hip/hip_bf16.h>

// Problem constants
#define B_    64
#define T_    1000
#define IN_   257
#define HID_  40
#define G3_   120
#define OUT_  257
#define M_    (B_*T_)   // 64000
#define NGI_  480
#define KP_   736       // padded KAN feature dim (720 real) = 92 groups of 8
#define KP1_  288       // padded GEMM1 K (257 real)
#define NP_   288       // padded OUT_ for k3 (18x16 cols)

// ws layout:
// gi0 240x64000 bf16 (layer0 gates, col-major; fwd | bwd)   = 30,720,000
// gi1 240x64000 bf16 (layer1 gates, col-major)              = 30,720,000
// P   column-block-major [92][64000][8] bf16                = 94,208,000
// Wk  288x736 bf16                                          =    423,936
// Wb  480x288 bf16                                          =    276,480
// WhT [2][128][64] bf16 (Whh1 gates x k, k40=bias, pad 0)   =     32,768
// h0R [2*M][64] bf16 row-major (k40=1.0, 41..63=0)          = 16,384,000
// h0C [2][40][M] bf16 col-major                             = 10,240,000
// ghC [2][120][M] bf16 col-major (gh = Whh1@h0 + bhh1)      = 30,720,000
#define OFF_GI1 30720000ull
#define OFF_P   61440000ull
#define OFF_WK  (OFF_P + 94208000ull)
#define OFF_WB  (OFF_WK + 423936ull)
#define OFF_WHT (OFF_WB + 276480ull)
#define OFF_H0R (OFF_WHT + 32768ull)
#define OFF_H0C (OFF_H0R + 16384000ull)
#define OFF_GHC (OFF_H0C + 10240000ull)
// end = OFF_GHC + 30,720,000 = 213,725,184 B

typedef __attribute__((ext_vector_type(8))) short bfx8;   // 8 bf16 = 4 VGPR
typedef __attribute__((ext_vector_type(4))) short bfx4;   // 8 B
typedef __attribute__((ext_vector_type(4))) float f32x4;  // MFMA C/D

__device__ __forceinline__ float sigf(float x){ return 1.0f/(1.0f + __expf(-x)); }
__device__ __forceinline__ float tanhfast(float x){ return 1.0f - 2.0f/(__expf(2.0f*x)+1.0f); }

__device__ __forceinline__ short bfbits(float v){
    __hip_bfloat16 h = __float2bfloat16(v);
    return *(short*)&h;
}
__device__ __forceinline__ float b2f(short s){
    return __uint_as_float(((unsigned)(unsigned short)s) << 16);
}

// Pack Wk[288][736] bf16 (rows 257..287 zero)
__global__ __launch_bounds__(256) void kprep(const float* __restrict__ bw,
                                             const float* __restrict__ sw,
                                             const float* __restrict__ ss,
                                             __hip_bfloat16* __restrict__ wk){
    int idx = blockIdx.x*256 + threadIdx.x;
    if (idx >= NP_*(KP_/8)) return;
    int o = idx / (KP_/8), q = idx % (KP_/8);
    bfx8 pk;
#pragma unroll
    for (int e=0;e<8;e++){
        int k = q*8 + e;
        float v = 0.0f;
        if (o < OUT_ && k < 720){
            if (k < 80) v = bw[o*80 + k];
            else { int i = (k-80)>>3, m = (k-80)&7; v = sw[(o*80+i)*8 + m] * ss[o*80+i]; }
        }
        pk[e] = bfbits(v);
    }
    *(bfx8*)((void*)&wk[(size_t)o*KP_ + q*8]) = pk;
}

// Pack Wb[480][288] bf16 from Wih_f | Wih_b, plus WhT[2][128][64] bf16:
// WhT[d][gate][k] = Whh1[d][gate][k] (k<40), bhh1[d][gate] (k==40), else 0.
__global__ __launch_bounds__(256) void wprep(const float* __restrict__ Wf,
                                             const float* __restrict__ Wbk,
                                             const float* __restrict__ Whh_f,
                                             const float* __restrict__ Whh_b,
                                             const float* __restrict__ bhh_f,
                                             const float* __restrict__ bhh_b,
                                             __hip_bfloat16* __restrict__ wb,
                                             __hip_bfloat16* __restrict__ wht){
    int idx = blockIdx.x*256 + threadIdx.x;
    if (idx < NGI_*(KP1_/8)){
        int n = idx / (KP1_/8), q = idx % (KP1_/8);
        bfx8 pk;
#pragma unroll
        for (int e=0;e<8;e++){
            int k = q*8 + e;
            float v = 0.0f;
            if (k < IN_) v = (n < 240) ? Wf[(size_t)n*IN_ + k] : Wbk[(size_t)(n-240)*IN_ + k];
            pk[e] = bfbits(v);
        }
        *(bfx8*)((void*)&wb[(size_t)n*KP1_ + q*8]) = pk;
        return;
    }
    int i2 = idx - NGI_*(KP1_/8);
    if (i2 >= 2*128*8) return;
    int d = i2 >> 10;            // 0..1
    int rest = i2 & 1023;
    int gate = rest >> 3, q = rest & 7;
    const float* Whh = d ? Whh_b : Whh_f;
    const float* bhh = d ? bhh_b : bhh_f;
    bfx8 pk;
#pragma unroll
    for (int e=0;e<8;e++){
        int k = q*8 + e;
        float v = 0.0f;
        if (gate < G3_){
            if (k < 40) v = Whh[G3_*HID_ + gate*HID_ + k];
            else if (k == 40) v = bhh[G3_ + gate];
        }
        pk[e] = bfbits(v);
    }
    *(bfx8*)((void*)&wht[(size_t)(d*128 + gate)*64 + q*8]) = pk;
}

// GEMM1 v3 (fixed): 2-phase register-staged dbuf pipeline; block = 128 rows x
// ALL 480 gates so X is fetched exactly once. 8 waves: wr 0..3 (32 rows),
// wc 0..1 (240 gates). K-step 32, 9 steps. LDS 97 KB.
// NOTE: macro-internal chunk index is `ci` (NOT `c`) — the buffer-index arg
// `bufi` expands textually to `c^1`, which must resolve to the OUTER c.
__global__ __launch_bounds__(512) void k1_gemm(const float* __restrict__ X,
                                               const __hip_bfloat16* __restrict__ Wb16,
                                               const float* __restrict__ bf,
                                               const float* __restrict__ bb,
                                               __hip_bfloat16* __restrict__ gi0,
                                               __hip_bfloat16* __restrict__ gi1){
    __shared__ __hip_bfloat16 Asm[2][128*40];
    __shared__ __hip_bfloat16 Bsm[2][480*40];
    int tid = threadIdx.x, wave = tid>>6, lane = tid&63;
    int wr = wave>>1, wc = wave&1;
    int rl = lane&15, kq = lane>>4;
    int m0 = blockIdx.x*128;

    int rA = tid>>2, qA = tid&3;   // A: row 0..127, k-slot 0..3
    f32x4 acc[2][15];
#pragma unroll
    for (int f=0;f<2;f++)
#pragma unroll
        for (int j=0;j<15;j++) acc[f][j] = (f32x4){0.f,0.f,0.f,0.f};

    bfx8 ra, rb[4];

#define K1_LOAD(tt) { \
    int k0 = (tt)*32; \
    { int kg = k0 + qA*8; \
      const float* xp = &X[(size_t)(m0+rA)*IN_ + kg]; \
      if (kg + 7 < IN_){ \
          f32x4 x0 = *(const f32x4*)xp; \
          f32x4 x1 = *(const f32x4*)(xp+4); \
          _Pragma("unroll") \
          for (int e=0;e<4;e++){ ra[e] = bfbits(x0[e]); ra[4+e] = bfbits(x1[e]); } \
      } else { \
          _Pragma("unroll") \
          for (int e=0;e<8;e++){ int k = kg + e; ra[e] = (k < IN_) ? bfbits(xp[e]) : (short)0; } \
      } } \
    _Pragma("unroll") \
    for (int p=0;p<4;p++){ \
        int ci = tid + p*512; \
        if (ci < 1920){ \
            int r = ci>>2, q = ci&3; \
            rb[p] = *(const bfx8*)&Wb16[(size_t)r*KP1_ + k0 + q*8]; \
        } } }

#define K1_WRITE(bufi) { \
    *(bfx8*)((void*)&Asm[bufi][rA*40 + qA*8]) = ra; \
    _Pragma("unroll") \
    for (int p=0;p<4;p++){ \
        int ci = tid + p*512; \
        if (ci < 1920){ \
            int r = ci>>2, q = ci&3; \
            *(bfx8*)((void*)&Bsm[bufi][r*40 + q*8]) = rb[p]; \
        } } }

    K1_LOAD(0); K1_WRITE(0); __syncthreads();
    for (int t=0; t<9; ++t){
        int c = t&1;
        if (t < 8) K1_LOAD(t+1);
        bfx8 a0 = *(bfx8*)((void*)&Asm[c][(wr*32 + rl)*40 + kq*8]);
        bfx8 a1 = *(bfx8*)((void*)&Asm[c][(wr*32 + 16 + rl)*40 + kq*8]);
#pragma unroll
        for (int j=0;j<15;j++){
            bfx8 b = *(bfx8*)((void*)&Bsm[c][(wc*240 + j*16 + rl)*40 + kq*8]);
            acc[0][j] = __builtin_amdgcn_mfma_f32_16x16x32_bf16(a0, b, acc[0][j], 0,0,0);
            acc[1][j] = __builtin_amdgcn_mfma_f32_16x16x32_bf16(a1, b, acc[1][j], 0,0,0);
        }
        if (t < 8) K1_WRITE(c^1);
        __syncthreads();
    }

#pragma unroll
    for (int j=0;j<15;j++){
        int n = wc*240 + j*16 + rl;          // 0..479
        float bias = (n < 240) ? bf[n] : bb[n-240];
        int d  = (n >= 240) ? 1 : 0;
        int nn = n - 240*d;
#pragma unroll
        for (int f=0;f<2;f++){
            int mb = m0 + wr*32 + f*16 + kq*4;
            bfx4 v;
#pragma unroll
            for (int r=0;r<4;r++) v[r] = bfbits(acc[f][j][r] + bias);
            if (nn < 120){
                *(bfx4*)((void*)&gi0[(size_t)(d*120 + nn)*M_ + mb]) = v;
            } else {
                *(bfx4*)((void*)&gi1[(size_t)(d*120 + nn - 120)*M_ + mb]) = v;
            }
        }
    }
}

// k2a: pure pointwise layer-0. Writes h0R bf16 row-major (GEMM A operand,
// slot 40 = 1.0 for folded bias) and h0C bf16 col-major (for k2c).
__global__ __launch_bounds__(256) void k2a(const __hip_bfloat16* __restrict__ gi0,
                                           const float* __restrict__ bhh_f,
                                           const float* __restrict__ bhh_b,
                                           __hip_bfloat16* __restrict__ h0R,
                                           __hip_bfloat16* __restrict__ h0C){
    int blk = blockIdx.x;                       // 0..499; dir uniform
    int dir = (blk >= 250) ? 1 : 0;
    int m = (blk - dir*250)*256 + threadIdx.x;
    int b = m / T_, t = m - b*T_;
    int src = dir ? (b*T_ + (T_-1-t)) : m;
    const float* bhh0v = dir ? bhh_b : bhh_f;

    const __hip_bfloat16* g0 = gi0 + (size_t)(dir*120)*M_ + src;
    __hip_bfloat16* hc = h0C + (size_t)(dir*40)*M_ + m;
    float h0[HID_];
#pragma unroll
    for (int j=0;j<HID_;j++){
        float ir = b2f(*(const short*)&g0[(size_t)j*M_]);
        float iz = b2f(*(const short*)&g0[(size_t)(40+j)*M_]);
        float in = b2f(*(const short*)&g0[(size_t)(80+j)*M_]);
        float r = sigf(ir + bhh0v[j]);
        float z = sigf(iz + bhh0v[40+j]);
        float n = tanhfast(in + r*bhh0v[80+j]);
        h0[j] = (1.0f - z)*n;
        hc[(size_t)j*M_] = __float2bfloat16(h0[j]);
    }
    __hip_bfloat16* hr = h0R + (size_t)(dir*M_ + m)*64;
#pragma unroll
    for (int q=0;q<8;q++){
        bfx8 v;
#pragma unroll
        for (int e=0;e<8;e++){
            int idx = q*8 + e;
            float f = (idx < HID_) ? h0[idx] : (idx == HID_ ? 1.0f : 0.0f);
            v[e] = bfbits(f);
        }
        *(bfx8*)((void*)&hr[q*8]) = v;
    }
}

// k2b: gh GEMM on MFMA. C[256 m][128 gate] = h0R[256x64] @ WhT[128x64]^T per block.
// Single LDS stage (K=64), XOR-swizzled (128B rows -> 16-way conflict otherwise).
__global__ __launch_bounds__(512) void k2b(const __hip_bfloat16* __restrict__ h0R,
                                           const __hip_bfloat16* __restrict__ WhT,
                                           __hip_bfloat16* __restrict__ ghC){
    __shared__ __hip_bfloat16 Ah[256*64];
    __shared__ __hip_bfloat16 Bh[128*64];
    int tid = threadIdx.x, wave = tid>>6, lane = tid&63;
    int wr = wave>>1, wc = wave&1;
    int rl = lane&15, kq = lane>>4;
    int blk = blockIdx.x;
    int dir = (blk >= 250) ? 1 : 0;
    int m0 = (blk - dir*250)*256;

#pragma unroll
    for (int p=0;p<4;p++){
        int cc = tid + p*512;
        int row = cc>>3, q = cc&7;
        bfx8 v = *(const bfx8*)&h0R[(size_t)(dir*M_ + m0 + row)*64 + q*8];
        *(bfx8*)((void*)&Ah[row*64 + ((q ^ (row&7))<<3)]) = v;
    }
#pragma unroll
    for (int p=0;p<2;p++){
        int cc = tid + p*512;
        int row = cc>>3, q = cc&7;
        bfx8 v = *(const bfx8*)&WhT[(size_t)(dir*128 + row)*64 + q*8];
        *(bfx8*)((void*)&Bh[row*64 + ((q ^ (row&7))<<3)]) = v;
    }
    __syncthreads();

    f32x4 acc[4][4];
#pragma unroll
    for (int f=0;f<4;f++)
#pragma unroll
        for (int j=0;j<4;j++) acc[f][j] = (f32x4){0.f,0.f,0.f,0.f};

#pragma unroll
    for (int ks=0;ks<2;ks++){
        bfx8 a[4], bb[4];
#pragma unroll
        for (int f=0;f<4;f++){
            int row = wr*64 + f*16 + rl;
            a[f] = *(bfx8*)((void*)&Ah[row*64 + (((ks*4+kq) ^ (row&7))<<3)]);
        }
#pragma unroll
        for (int j=0;j<4;j++){
            int row = wc*64 + j*16 + rl;
            bb[j] = *(bfx8*)((void*)&Bh[row*64 + (((ks*4+kq) ^ (row&7))<<3)]);
        }
#pragma unroll
        for (int f=0;f<4;f++)
#pragma unroll
            for (int j=0;j<4;j++)
                acc[f][j] = __builtin_amdgcn_mfma_f32_16x16x32_bf16(a[f], bb[j], acc[f][j], 0,0,0);
    }
#pragma unroll
    for (int j=0;j<4;j++){
        int n = wc*64 + j*16 + rl;
        if (n < G3_){
#pragma unroll
            for (int f=0;f<4;f++){
                int mb = m0 + wr*64 + f*16 + kq*4;
                bfx4 v;
#pragma unroll
                for (int r=0;r<4;r++) v[r] = bfbits(acc[f][j][r]);
                *(bfx4*)((void*)&ghC[(size_t)(dir*G3_ + n)*M_ + mb]) = v;
            }
        }
    }
}

// k2c: thread = (m, dir, 8-feature group). Pure streaming pointwise:
// GRU layer-1 gates from gi1+ghC, silu, closed-form uniform cubic B-spline,
// coalesced bfx8 stores into column-block-major P. No LDS, no matvec.
__global__ __launch_bounds__(256, 4) void k2c(const __hip_bfloat16* __restrict__ gi1,
                                              const __hip_bfloat16* __restrict__ ghC,
                                              const __hip_bfloat16* __restrict__ h0C,
                                              __hip_bfloat16* __restrict__ P){
    int tid = threadIdx.x;
    int bb = blockIdx.x;            // 0..2499
    int mblk = bb % 250;
    int rest = bb / 250;            // 0..9
    int dir = rest / 5, grp = rest % 5;
    int m = mblk*256 + tid;
    int b = m / T_, t = m - b*T_;
    int src = dir ? (b*T_ + (T_-1-t)) : m;

    const __hip_bfloat16* g1 = gi1 + (size_t)(dir*120)*M_ + src;
    const __hip_bfloat16* gh = ghC + (size_t)(dir*120)*M_ + m;
    const __hip_bfloat16* hc = h0C + (size_t)(dir*40)*M_ + m;

    bfx8 sil;
#pragma unroll
    for (int jj=0;jj<8;jj++){
        int j = grp*8 + jj;
        float ir = b2f(*(const short*)&g1[(size_t)j*M_]);
        float iz = b2f(*(const short*)&g1[(size_t)(40+j)*M_]);
        float in = b2f(*(const short*)&g1[(size_t)(80+j)*M_]);
        float gr = b2f(*(const short*)&gh[(size_t)j*M_]);
        float gz = b2f(*(const short*)&gh[(size_t)(40+j)*M_]);
        float gn = b2f(*(const short*)&gh[(size_t)(80+j)*M_]);
        float r = sigf(ir + gr);
        float z = sigf(iz + gz);
        float n = tanhfast(in + r*gn);
        float h1 = (1.0f - z)*n + z*b2f(*(const short*)&hc[(size_t)j*M_]);
        sil[jj] = bfbits(h1 * sigf(h1));

        // closed-form uniform cubic B-spline: knots t_p=(p-3)*0.4-1, h=0.4
        float tt = (h1 + 1.0f) * 2.5f;
        float fs = floorf(tt);
        fs = fminf(fmaxf(fs, 0.0f), 4.0f);
        int sp = (int)fs;
        float u  = tt - fs;
        float um = 1.0f - u;
        float u2 = u*u, u3 = u2*u;
        float N0 = um*um*um * (1.0f/6.0f);
        float N1 = (3.0f*u3 - 6.0f*u2 + 4.0f) * (1.0f/6.0f);
        float N2 = (-3.0f*u3 + 3.0f*u2 + 3.0f*u + 1.0f) * (1.0f/6.0f);
        float N3 = u3 * (1.0f/6.0f);
        bfx8 pk;
#pragma unroll
        for (int i=0;i<8;i++){
            int d = i - sp;
            float v = (d==0)?N0 : (d==1)?N1 : (d==2)?N2 : (d==3)?N3 : 0.0f;
            pk[i] = bfbits(v);
        }
        *(bfx8*)((void*)&P[((size_t)(10 + dir*40 + j)*M_ + m)*8]) = pk;
    }
    *(bfx8*)((void*)&P[((size_t)(dir*5 + grp)*M_ + m)*8]) = sil;
    if (dir==0 && grp==0){   // zero K-pad groups 90,91 (logical cols 720..735)
        bfx8 z8 = {0,0,0,0,0,0,0,0};
        *(bfx8*)((void*)&P[((size_t)90*M_ + m)*8]) = z8;
        *(bfx8*)((void*)&P[((size_t)91*M_ + m)*8]) = z8;
    }
}

// GEMM2 (MFMA, pipelined dbuf): M-tile 256, N 288 (all), 8 waves (4x2).
__global__ __launch_bounds__(512) void k3_gemm(const __hip_bfloat16* __restrict__ P,
                                               const __hip_bfloat16* __restrict__ Wk,
                                               const float* __restrict__ slope,
                                               float* __restrict__ outp){
    __shared__ __hip_bfloat16 Asm[2][256*40];
    __shared__ __hip_bfloat16 Bsm[2][NP_*40];
    int tid = threadIdx.x, wave = tid>>6, lane = tid&63;
    int wr = wave>>1, wc = wave&1;
    int rl = lane&15, kq = lane>>4;
    int m0 = blockIdx.x*256;

    int qA = tid>>8, rA = tid&255;
    int rB = tid>>2, qB = tid&3;

    f32x4 acc[4][9];
#pragma unroll
    for (int f=0;f<4;f++)
#pragma unroll
        for (int j=0;j<9;j++) acc[f][j] = (f32x4){0.f,0.f,0.f,0.f};

    bfx8 ra[2], rb[3];

#define K3_LOAD(tt) { \
    int k8 = (tt)*4, k0 = (tt)*32; \
    ra[0] = *(const bfx8*)&P[((size_t)(k8+qA)*M_ + m0 + rA)*8]; \
    ra[1] = *(const bfx8*)&P[((size_t)(k8+qA+2)*M_ + m0 + rA)*8]; \
    rb[0] = *(const bfx8*)&Wk[(size_t)rB*KP_ + k0 + qB*8]; \
    rb[1] = *(const bfx8*)&Wk[(size_t)(rB+128)*KP_ + k0 + qB*8]; \
    if (tid < 128) rb[2] = *(const bfx8*)&Wk[(size_t)(rB+256)*KP_ + k0 + qB*8]; }

#define K3_WRITE(bufi) { \
    *(bfx8*)((void*)&Asm[bufi][rA*40 + qA*8]) = ra[0]; \
    *(bfx8*)((void*)&Asm[bufi][rA*40 + (qA+2)*8]) = ra[1]; \
    *(bfx8*)((void*)&Bsm[bufi][rB*40 + qB*8]) = rb[0]; \
    *(bfx8*)((void*)&Bsm[bufi][(rB+128)*40 + qB*8]) = rb[1]; \
    if (tid < 128) *(bfx8*)((void*)&Bsm[bufi][(rB+256)*40 + qB*8]) = rb[2]; }

    K3_LOAD(0); K3_WRITE(0); __syncthreads();
    for (int t=0; t<23; ++t){
        int c = t&1;
        if (t < 22) K3_LOAD(t+1);
        bfx8 a[4];
#pragma unroll
        for (int f=0;f<4;f++)
            a[f] = *(bfx8*)((void*)&Asm[c][(wr*64 + f*16 + rl)*40 + kq*8]);
#pragma unroll
        for (int j=0;j<9;j++){
            bfx8 b = *(bfx8*)((void*)&Bsm[c][(wc*144 + j*16 + rl)*40 + kq*8]);
#pragma unroll
            for (int f=0;f<4;f++)
                acc[f][j] = __builtin_amdgcn_mfma_f32_16x16x32_bf16(a[f], b, acc[f][j], 0,0,0);
        }
        if (t < 22) K3_WRITE(c^1);
        __syncthreads();
    }
#pragma unroll
    for (int j=0;j<9;j++){
        int n = wc*144 + j*16 + rl;
        if (n < OUT_){
            float sl = slope[n];
#pragma unroll
            for (int f=0;f<4;f++){
                int mb = m0 + wr*64 + f*16 + kq*4;
#pragma unroll
                for (int r=0;r<4;r++)
                    outp[(size_t)(mb+r)*OUT_ + n] = 1.2f * sigf(sl*acc[f][j][r]);
            }
        }
    }
}

extern "C" void kernel_launch(void* const* d_in, const int* in_sizes, int n_in,
                              void* d_out, int out_size, void* d_ws, size_t ws_size,
                              hipStream_t stream) {
    const float* x      = (const float*)d_in[0];
    const float* Wih_f  = (const float*)d_in[1];
    const float* Whh_f  = (const float*)d_in[2];
    const float* bih_f  = (const float*)d_in[3];
    const float* bhh_f  = (const float*)d_in[4];
    const float* Wih_b  = (const float*)d_in[5];
    const float* Whh_b  = (const float*)d_in[6];
    const float* bih_b  = (const float*)d_in[7];
    const float* bhh_b  = (const float*)d_in[8];
    const float* base_w = (const float*)d_in[9];
    const float* spl_w  = (const float*)d_in[10];
    const float* spl_s  = (const float*)d_in[11];
    const float* slope  = (const float*)d_in[12];

    char* ws = (char*)d_ws;
    __hip_bfloat16* gi0 = (__hip_bfloat16*)ws;
    __hip_bfloat16* gi1 = (__hip_bfloat16*)(ws + OFF_GI1);
    __hip_bfloat16* P   = (__hip_bfloat16*)(ws + OFF_P);
    __hip_bfloat16* Wk  = (__hip_bfloat16*)(ws + OFF_WK);
    __hip_bfloat16* Wb  = (__hip_bfloat16*)(ws + OFF_WB);
    __hip_bfloat16* WhT = (__hip_bfloat16*)(ws + OFF_WHT);
    __hip_bfloat16* h0R = (__hip_bfloat16*)(ws + OFF_H0R);
    __hip_bfloat16* h0C = (__hip_bfloat16*)(ws + OFF_H0C);
    __hip_bfloat16* ghC = (__hip_bfloat16*)(ws + OFF_GHC);
    float* outp = (float*)d_out;

    hipLaunchKernelGGL(kprep, dim3((NP_*(KP_/8) + 255)/256), dim3(256), 0, stream,
                       base_w, spl_w, spl_s, Wk);
    hipLaunchKernelGGL(wprep, dim3((NGI_*(KP1_/8) + 2048 + 255)/256), dim3(256), 0, stream,
                       Wih_f, Wih_b, Whh_f, Whh_b, bhh_f, bhh_b, Wb, WhT);
    hipLaunchKernelGGL(k1_gemm, dim3(500), dim3(512), 0, stream,
                       x, Wb, bih_f, bih_b, gi0, gi1);
    hipLaunchKernelGGL(k2a, dim3(500), dim3(256), 0, stream,
                       gi0, bhh_f, bhh_b, h0R, h0C);
    hipLaunchKernelGGL(k2b, dim3(500), dim3(512), 0, stream,
                       h0R, WhT, ghC);
    hipLaunchKernelGGL(k2c, dim3(2500), dim3(256), 0, stream,
                       gi1, ghC, h0C, P);
    hipLaunchKernelGGL(k3_gemm, dim3(250), dim3(512), 0, stream,
                       P, Wk, slope, outp);
}